// Round 1
// baseline (260.743 us; speedup 1.0000x reference)
//
#include <hip/hip_runtime.h>

typedef short bf16x8 __attribute__((ext_vector_type(8)));
typedef float f32x4 __attribute__((ext_vector_type(4)));

#define T_TOK 1024
#define DIM   1024
#define KCAT  7168
#define PADK  72   // padded LDS row length in bf16 elems (144B stride, 16B aligned)

__device__ __forceinline__ ushort f2bf(float f) {
  unsigned u = __float_as_uint(f);
  u += 0x7fffu + ((u >> 16) & 1u);   // round-to-nearest-even
  return (ushort)(u >> 16);
}

// ---------------------------------------------------------------------------
// Router: fp32 logits for the token's modality, softmax, biased top-2,
// normalized weights -> dense comb matrices. Also writes router_logits output
// and the bf16 copy of X.
// ---------------------------------------------------------------------------
__global__ __launch_bounds__(256) void router_kernel(
    const float* __restrict__ x, const int* __restrict__ tt,
    const float* __restrict__ t_rw, const float* __restrict__ t_bias,
    const float* __restrict__ v_rw, const float* __restrict__ v_bias,
    float* __restrict__ comb_t, float* __restrict__ comb_v,
    float* __restrict__ logits_out, ushort* __restrict__ xb) {
  int t = blockIdx.x * 4 + (threadIdx.x >> 6);
  int lane = threadIdx.x & 63;
  const float* xr = x + (size_t)t * DIM;
  int vis = tt[t] != 0;
  const float* rw   = vis ? v_rw   : t_rw;
  const float* bias = vis ? v_bias : t_bias;
  float xv[16];
#pragma unroll
  for (int i = 0; i < 16; ++i) {
    float v = xr[lane + 64 * i];
    xv[i] = v;
    xb[(size_t)t * DIM + lane + 64 * i] = f2bf(v);
  }
  float lg[8];
#pragma unroll
  for (int e = 0; e < 8; ++e) {
    const float* wrow = rw + (size_t)e * DIM;
    float s = 0.f;
#pragma unroll
    for (int i = 0; i < 16; ++i) s += xv[i] * wrow[lane + 64 * i];
#pragma unroll
    for (int off = 32; off > 0; off >>= 1) s += __shfl_xor(s, off);
    lg[e] = s;
  }
  if (lane == 0) {
    float mx = lg[0];
    for (int e = 1; e < 8; ++e) mx = fmaxf(mx, lg[e]);
    float ex[8]; float sum = 0.f;
    for (int e = 0; e < 8; ++e) { ex[e] = __expf(lg[e] - mx); sum += ex[e]; }
    float inv = 1.f / sum;
    float pr[8], sc[8];
    for (int e = 0; e < 8; ++e) { pr[e] = ex[e] * inv; sc[e] = pr[e] + bias[e]; }
    int i0 = 0;
    for (int e = 1; e < 8; ++e) if (sc[e] > sc[i0]) i0 = e;   // first max on tie
    int i1 = -1;
    for (int e = 0; e < 8; ++e) {
      if (e == i0) continue;
      if (i1 < 0 || sc[e] > sc[i1]) i1 = e;
    }
    float w0 = pr[i0], w1 = pr[i1];
    float s2 = fmaxf(w0 + w1, 1e-12f);
    w0 /= s2; w1 /= s2;
    float* ct = comb_t + (size_t)t * 8;
    float* cv = comb_v + (size_t)t * 8;
    for (int e = 0; e < 8; ++e) { ct[e] = 0.f; cv[e] = 0.f; }
    float* sel = vis ? cv : ct;
    sel[i0] = w0; sel[i1] = w1;
    for (int e = 0; e < 8; ++e) logits_out[(size_t)t * 8 + e] = lg[e];
  }
}

// ---------------------------------------------------------------------------
// Transpose fp32 [R][C] -> bf16 [C][R]  (batched via blockIdx.z)
// ---------------------------------------------------------------------------
__global__ __launch_bounds__(256) void transpose_bf16_kernel(
    const float* __restrict__ src, ushort* __restrict__ dst, int R, int C) {
  __shared__ float tile[32][33];
  size_t boff = (size_t)blockIdx.z * R * C;
  src += boff; dst += boff;
  int c0 = blockIdx.x * 32, r0 = blockIdx.y * 32;
  int tx = threadIdx.x, ty = threadIdx.y;   // 32 x 8
#pragma unroll
  for (int i = 0; i < 32; i += 8)
    tile[ty + i][tx] = src[(size_t)(r0 + ty + i) * C + c0 + tx];
  __syncthreads();
#pragma unroll
  for (int i = 0; i < 32; i += 8)
    dst[(size_t)(c0 + ty + i) * R + r0 + tx] = f2bf(tile[tx][ty + i]);
}

// ---------------------------------------------------------------------------
// Phase A: H[t, col] = silu(x@g) * (x@u) * comb   (col-concat layout, K=1024)
// BM=128, BN=64, BK=64; 4 waves (2x2), wave tile 64x32; dual accumulators.
// grid.x = 8 m-tiles * 112 n-tiles = 896
// ---------------------------------------------------------------------------
__global__ __launch_bounds__(256) void moe_up_kernel(
    const ushort* __restrict__ Xb,
    const ushort* __restrict__ swgT, const ushort* __restrict__ swuT,
    const ushort* __restrict__ twgT, const ushort* __restrict__ twuT,
    const ushort* __restrict__ vwgT, const ushort* __restrict__ vwuT,
    const float* __restrict__ comb_t, const float* __restrict__ comb_v,
    ushort* __restrict__ H) {
  __shared__ ushort lA[128 * PADK];
  __shared__ ushort lBg[64 * PADK];
  __shared__ ushort lBu[64 * PADK];

  int bid = blockIdx.x;
  int mt  = bid & 7;
  int ntg = bid >> 3;          // 0..111
  int t0  = mt * 128;
  const ushort *Bg, *Bu;
  const float* combp = nullptr;
  int hcol;
  if (ntg < 16) {              // shared experts, F=1024
    int nl = ntg * 64;
    Bg = swgT + (size_t)nl * DIM; Bu = swuT + (size_t)nl * DIM;
    hcol = nl;
  } else if (ntg < 80) {       // text experts, F=512
    int tI = ntg - 16; int e = tI >> 3; int nl = (tI & 7) * 64;
    size_t off = ((size_t)e * 512 + nl) * DIM;
    Bg = twgT + off; Bu = twuT + off;
    combp = comb_t + e;
    hcol = 1024 + e * 512 + nl;
  } else {                     // vision experts, F=256
    int vI = ntg - 80; int e = vI >> 2; int nl = (vI & 3) * 64;
    size_t off = ((size_t)e * 256 + nl) * DIM;
    Bg = vwgT + off; Bu = vwuT + off;
    combp = comb_v + e;
    hcol = 5120 + e * 256 + nl;
  }

  int tid = threadIdx.x;
  int lane = tid & 63, w = tid >> 6;
  int wm = w >> 1, wn = w & 1;
  int fr = lane & 15, fq = lane >> 4;

  f32x4 accg[4][2] = {}; f32x4 accu[4][2] = {};

  for (int k0 = 0; k0 < DIM; k0 += 64) {
    __syncthreads();
#pragma unroll
    for (int i = 0; i < 4; ++i) {
      int c = tid + 256 * i; int row = c >> 3, kc = c & 7;
      *(uint4*)&lA[row * PADK + kc * 8] =
          *(const uint4*)(Xb + (size_t)(t0 + row) * DIM + k0 + kc * 8);
    }
#pragma unroll
    for (int i = 0; i < 2; ++i) {
      int c = tid + 256 * i; int row = c >> 3, kc = c & 7;
      *(uint4*)&lBg[row * PADK + kc * 8] =
          *(const uint4*)(Bg + (size_t)row * DIM + k0 + kc * 8);
      *(uint4*)&lBu[row * PADK + kc * 8] =
          *(const uint4*)(Bu + (size_t)row * DIM + k0 + kc * 8);
    }
    __syncthreads();
#pragma unroll
    for (int kk = 0; kk < 2; ++kk) {
      int kb = kk * 32 + fq * 8;
      bf16x8 a[4], bg[2], bu[2];
#pragma unroll
      for (int m = 0; m < 4; ++m)
        a[m] = *(const bf16x8*)&lA[(wm * 64 + m * 16 + fr) * PADK + kb];
#pragma unroll
      for (int n = 0; n < 2; ++n) {
        bg[n] = *(const bf16x8*)&lBg[(wn * 32 + n * 16 + fr) * PADK + kb];
        bu[n] = *(const bf16x8*)&lBu[(wn * 32 + n * 16 + fr) * PADK + kb];
      }
#pragma unroll
      for (int m = 0; m < 4; ++m)
#pragma unroll
        for (int n = 0; n < 2; ++n) {
          accg[m][n] = __builtin_amdgcn_mfma_f32_16x16x32_bf16(a[m], bg[n], accg[m][n], 0, 0, 0);
          accu[m][n] = __builtin_amdgcn_mfma_f32_16x16x32_bf16(a[m], bu[n], accu[m][n], 0, 0, 0);
        }
    }
  }

#pragma unroll
  for (int m = 0; m < 4; ++m) {
    int tb = t0 + wm * 64 + m * 16 + fq * 4;
    float cv[4];
#pragma unroll
    for (int r = 0; r < 4; ++r)
      cv[r] = combp ? combp[(size_t)(tb + r) * 8] : 1.0f;
#pragma unroll
    for (int n = 0; n < 2; ++n) {
      int col = hcol + wn * 32 + n * 16 + fr;
#pragma unroll
      for (int r = 0; r < 4; ++r) {
        float g = accg[m][n][r], u = accu[m][n][r];
        float h = g / (1.f + __expf(-g)) * u * cv[r];
        H[(size_t)(tb + r) * KCAT + col] = f2bf(h);
      }
    }
  }
}

// ---------------------------------------------------------------------------
// Phase B: out = H @ [Wd_shared; Wd_text; Wd_vis]   M=N=1024, K=7168
// BM=BN=64, BK=64; 4 waves (2x2), wave tile 32x32. grid (16,16) = 256 blocks.
// ---------------------------------------------------------------------------
__global__ __launch_bounds__(256) void moe_down_kernel(
    const ushort* __restrict__ H,
    const ushort* __restrict__ swdT, const ushort* __restrict__ twdT,
    const ushort* __restrict__ vwdT,
    float* __restrict__ out) {
  __shared__ ushort lA[64 * PADK];
  __shared__ ushort lB[64 * PADK];
  int t0 = blockIdx.x * 64, n0 = blockIdx.y * 64;
  int tid = threadIdx.x, lane = tid & 63, w = tid >> 6;
  int wm = w >> 1, wn = w & 1;
  int fr = lane & 15, fq = lane >> 4;
  f32x4 acc[2][2] = {};

  for (int k0 = 0; k0 < KCAT; k0 += 64) {
    const ushort* Bp; int bs;
    if (k0 < 1024)      { Bp = swdT + k0; bs = 1024; }
    else if (k0 < 5120) { int e = (k0 - 1024) >> 9; int kk = (k0 - 1024) & 511;
                          Bp = twdT + (size_t)e * DIM * 512 + kk; bs = 512; }
    else                { int e = (k0 - 5120) >> 8; int kk = (k0 - 5120) & 255;
                          Bp = vwdT + (size_t)e * DIM * 256 + kk; bs = 256; }
    __syncthreads();
#pragma unroll
    for (int i = 0; i < 2; ++i) {
      int c = tid + 256 * i; int row = c >> 3, kc = c & 7;
      *(uint4*)&lA[row * PADK + kc * 8] =
          *(const uint4*)(H + (size_t)(t0 + row) * KCAT + k0 + kc * 8);
      *(uint4*)&lB[row * PADK + kc * 8] =
          *(const uint4*)(Bp + (size_t)(n0 + row) * bs + kc * 8);
    }
    __syncthreads();
#pragma unroll
    for (int kk = 0; kk < 2; ++kk) {
      int kb = kk * 32 + fq * 8;
      bf16x8 a[2], b[2];
#pragma unroll
      for (int m = 0; m < 2; ++m)
        a[m] = *(const bf16x8*)&lA[(wm * 32 + m * 16 + fr) * PADK + kb];
#pragma unroll
      for (int n = 0; n < 2; ++n)
        b[n] = *(const bf16x8*)&lB[(wn * 32 + n * 16 + fr) * PADK + kb];
#pragma unroll
      for (int m = 0; m < 2; ++m)
#pragma unroll
        for (int n = 0; n < 2; ++n)
          acc[m][n] = __builtin_amdgcn_mfma_f32_16x16x32_bf16(a[m], b[n], acc[m][n], 0, 0, 0);
    }
  }
#pragma unroll
  for (int m = 0; m < 2; ++m)
#pragma unroll
    for (int n = 0; n < 2; ++n)
#pragma unroll
      for (int r = 0; r < 4; ++r)
        out[(size_t)(t0 + wm * 32 + m * 16 + fq * 4 + r) * DIM
            + n0 + wn * 32 + n * 16 + fr] = acc[m][n][r];
}

// ---------------------------------------------------------------------------
extern "C" void kernel_launch(void* const* d_in, const int* in_sizes, int n_in,
                              void* d_out, int out_size, void* d_ws, size_t ws_size,
                              hipStream_t stream) {
  const float* x    = (const float*)d_in[0];
  const int*   tt   = (const int*)d_in[1];
  const float* t_rw = (const float*)d_in[2];
  const float* t_b  = (const float*)d_in[3];
  const float* t_wg = (const float*)d_in[4];
  const float* t_wu = (const float*)d_in[5];
  const float* t_wd = (const float*)d_in[6];
  const float* v_rw = (const float*)d_in[7];
  const float* v_b  = (const float*)d_in[8];
  const float* v_wg = (const float*)d_in[9];
  const float* v_wu = (const float*)d_in[10];
  const float* v_wd = (const float*)d_in[11];
  const float* s_wg = (const float*)d_in[12];
  const float* s_wu = (const float*)d_in[13];
  const float* s_wd = (const float*)d_in[14];
  float* out    = (float*)d_out;
  float* logits = out + (size_t)1024 * 1024;

  char* p = (char*)d_ws;
  auto alloc = [&](size_t bytes) {
    char* r = p; p += (bytes + 255) & ~(size_t)255; return r;
  };
  ushort* xb     = (ushort*)alloc((size_t)1024 * 1024 * 2);
  float*  comb_t = (float*)alloc((size_t)1024 * 8 * 4);
  float*  comb_v = (float*)alloc((size_t)1024 * 8 * 4);
  ushort* swgT   = (ushort*)alloc((size_t)1024 * 1024 * 2);
  ushort* swuT   = (ushort*)alloc((size_t)1024 * 1024 * 2);
  ushort* swdT   = (ushort*)alloc((size_t)1024 * 1024 * 2);
  ushort* twgT   = (ushort*)alloc((size_t)8 * 512 * 1024 * 2);
  ushort* twuT   = (ushort*)alloc((size_t)8 * 512 * 1024 * 2);
  ushort* twdT   = (ushort*)alloc((size_t)8 * 1024 * 512 * 2);
  ushort* vwgT   = (ushort*)alloc((size_t)8 * 256 * 1024 * 2);
  ushort* vwuT   = (ushort*)alloc((size_t)8 * 256 * 1024 * 2);
  ushort* vwdT   = (ushort*)alloc((size_t)8 * 1024 * 256 * 2);
  ushort* H      = (ushort*)alloc((size_t)1024 * KCAT * 2);

  dim3 tb(32, 8);
  transpose_bf16_kernel<<<dim3(32, 32, 1), tb, 0, stream>>>(s_wg, swgT, 1024, 1024);
  transpose_bf16_kernel<<<dim3(32, 32, 1), tb, 0, stream>>>(s_wu, swuT, 1024, 1024);
  transpose_bf16_kernel<<<dim3(32, 32, 1), tb, 0, stream>>>(s_wd, swdT, 1024, 1024);
  transpose_bf16_kernel<<<dim3(16, 32, 8), tb, 0, stream>>>(t_wg, twgT, 1024, 512);
  transpose_bf16_kernel<<<dim3(16, 32, 8), tb, 0, stream>>>(t_wu, twuT, 1024, 512);
  transpose_bf16_kernel<<<dim3(32, 16, 8), tb, 0, stream>>>(t_wd, twdT, 512, 1024);
  transpose_bf16_kernel<<<dim3(8, 32, 8),  tb, 0, stream>>>(v_wg, vwgT, 1024, 256);
  transpose_bf16_kernel<<<dim3(8, 32, 8),  tb, 0, stream>>>(v_wu, vwuT, 1024, 256);
  transpose_bf16_kernel<<<dim3(32, 8, 8),  tb, 0, stream>>>(v_wd, vwdT, 256, 1024);

  router_kernel<<<256, 256, 0, stream>>>(x, tt, t_rw, t_b, v_rw, v_b,
                                         comb_t, comb_v, logits, xb);
  moe_up_kernel<<<896, 256, 0, stream>>>(xb, swgT, swuT, twgT, twuT, vwgT, vwuT,
                                         comb_t, comb_v, H);
  moe_down_kernel<<<dim3(16, 16), 256, 0, stream>>>(H, swdT, twdT, vwdT, out);
}

// Round 2
// 115.396 us; speedup vs baseline: 2.2595x; 2.2595x over previous
//
#include <hip/hip_runtime.h>

typedef short bf16x8 __attribute__((ext_vector_type(8)));
typedef float f32x4 __attribute__((ext_vector_type(4)));

#define DIM   1024
#define KCAT  7168
#define NSPLIT 7
#define KSPL  1024

__device__ __forceinline__ ushort f2bf(float f) {
  unsigned u = __float_as_uint(f);
  u += 0x7fffu + ((u >> 16) & 1u);   // round-to-nearest-even
  return (ushort)(u >> 16);
}

__device__ __forceinline__ void gld16(const ushort* g, ushort* l) {
  __builtin_amdgcn_global_load_lds(
      (const __attribute__((address_space(1))) unsigned int*)g,
      (__attribute__((address_space(3))) unsigned int*)l, 16, 0, 0);
}

// ---------------------------------------------------------------------------
// Router: fp32 logits (token's modality), softmax, biased top-2, normalized
// weights -> dense comb matrices; also router_logits output + bf16 X copy.
// ---------------------------------------------------------------------------
__global__ __launch_bounds__(256) void router_kernel(
    const float* __restrict__ x, const int* __restrict__ tt,
    const float* __restrict__ t_rw, const float* __restrict__ t_bias,
    const float* __restrict__ v_rw, const float* __restrict__ v_bias,
    float* __restrict__ comb_t, float* __restrict__ comb_v,
    float* __restrict__ logits_out, ushort* __restrict__ xb) {
  int t = blockIdx.x * 4 + (threadIdx.x >> 6);
  int lane = threadIdx.x & 63;
  const float* xr = x + (size_t)t * DIM;
  int vis = tt[t] != 0;
  const float* rw   = vis ? v_rw   : t_rw;
  const float* bias = vis ? v_bias : t_bias;
  float xv[16];
#pragma unroll
  for (int i = 0; i < 16; ++i) {
    float v = xr[lane + 64 * i];
    xv[i] = v;
    xb[(size_t)t * DIM + lane + 64 * i] = f2bf(v);
  }
  float lg[8];
#pragma unroll
  for (int e = 0; e < 8; ++e) {
    const float* wrow = rw + (size_t)e * DIM;
    float s = 0.f;
#pragma unroll
    for (int i = 0; i < 16; ++i) s += xv[i] * wrow[lane + 64 * i];
#pragma unroll
    for (int off = 32; off > 0; off >>= 1) s += __shfl_xor(s, off);
    lg[e] = s;
  }
  if (lane == 0) {
    float mx = lg[0];
    for (int e = 1; e < 8; ++e) mx = fmaxf(mx, lg[e]);
    float ex[8]; float sum = 0.f;
    for (int e = 0; e < 8; ++e) { ex[e] = __expf(lg[e] - mx); sum += ex[e]; }
    float inv = 1.f / sum;
    float pr[8], sc[8];
    for (int e = 0; e < 8; ++e) { pr[e] = ex[e] * inv; sc[e] = pr[e] + bias[e]; }
    int i0 = 0;
    for (int e = 1; e < 8; ++e) if (sc[e] > sc[i0]) i0 = e;
    int i1 = -1;
    for (int e = 0; e < 8; ++e) {
      if (e == i0) continue;
      if (i1 < 0 || sc[e] > sc[i1]) i1 = e;
    }
    float w0 = pr[i0], w1 = pr[i1];
    float s2 = fmaxf(w0 + w1, 1e-12f);
    w0 /= s2; w1 /= s2;
    float* ct = comb_t + (size_t)t * 8;
    float* cv = comb_v + (size_t)t * 8;
    for (int e = 0; e < 8; ++e) { ct[e] = 0.f; cv[e] = 0.f; }
    float* sel = vis ? cv : ct;
    sel[i0] = w0; sel[i1] = w1;
    for (int e = 0; e < 8; ++e) logits_out[(size_t)t * 8 + e] = lg[e];
  }
}

// ---------------------------------------------------------------------------
// Merged weight prep: fp32 [R][C] (batched) -> bf16 [C][R], all 9 tensors
// in one launch. 21504 blocks of 256 threads, 32x32 tiles.
// ---------------------------------------------------------------------------
__global__ __launch_bounds__(256) void prep_kernel(
    const float* __restrict__ s_wg, const float* __restrict__ s_wu,
    const float* __restrict__ s_wd,
    const float* __restrict__ t_wg, const float* __restrict__ t_wu,
    const float* __restrict__ t_wd,
    const float* __restrict__ v_wg, const float* __restrict__ v_wu,
    const float* __restrict__ v_wd,
    ushort* __restrict__ swgT, ushort* __restrict__ swuT,
    ushort* __restrict__ swdT,
    ushort* __restrict__ twgT, ushort* __restrict__ twuT,
    ushort* __restrict__ twdT,
    ushort* __restrict__ vwgT, ushort* __restrict__ vwuT,
    ushort* __restrict__ vwdT) {
  int b = blockIdx.x;
  const float* src; ushort* dst; int R, C;
  if (b < 3072) {                       // shared: 3 x 1024 tiles
    int t = b >> 10; b &= 1023;
    src = t == 0 ? s_wg : (t == 1 ? s_wu : s_wd);
    dst = t == 0 ? swgT : (t == 1 ? swuT : swdT);
    R = 1024; C = 1024;
  } else if (b < 11264) {               // text wg/wu: 2 x 4096 tiles
    b -= 3072; int t = b >> 12; b &= 4095;
    src = t == 0 ? t_wg : t_wu; dst = t == 0 ? twgT : twuT;
    R = 1024; C = 512;
  } else if (b < 15360) {               // text wd: 4096 tiles
    b -= 11264; src = t_wd; dst = twdT; R = 512; C = 1024;
  } else if (b < 19456) {               // vis wg/wu: 2 x 2048 tiles
    b -= 15360; int t = b >> 11; b &= 2047;
    src = t == 0 ? v_wg : v_wu; dst = t == 0 ? vwgT : vwuT;
    R = 1024; C = 256;
  } else {                              // vis wd: 2048 tiles
    b -= 19456; src = v_wd; dst = vwdT; R = 256; C = 1024;
  }
  int tilesC = C >> 5, tilesR = R >> 5;
  int per = tilesR * tilesC;
  int z = b / per; int rem = b - z * per;
  int r0 = (rem / tilesC) << 5, c0 = (rem - (rem / tilesC) * tilesC) << 5;
  size_t boff = (size_t)z * R * C;
  src += boff; dst += boff;
  __shared__ float tile[32][33];
  int tx = threadIdx.x & 31, ty = threadIdx.x >> 5;   // 32 x 8
#pragma unroll
  for (int i = 0; i < 32; i += 8)
    tile[ty + i][tx] = src[(size_t)(r0 + ty + i) * C + c0 + tx];
  __syncthreads();
#pragma unroll
  for (int i = 0; i < 32; i += 8)
    dst[(size_t)(c0 + ty + i) * R + r0 + tx] = f2bf(tile[tx][ty + i]);
}

// ---------------------------------------------------------------------------
// Phase A: H[t, col] = silu(x@g) * (x@u) * comb   (col-concat, K=1024)
// BM=128, BN=64, BK=64; global_load_lds staging, linear LDS.
// 4 waves (2x2), wave tile 64x32, dual accumulators. grid = 896.
// ---------------------------------------------------------------------------
__global__ __launch_bounds__(256) void moe_up_kernel(
    const ushort* __restrict__ Xb,
    const ushort* __restrict__ swgT, const ushort* __restrict__ swuT,
    const ushort* __restrict__ twgT, const ushort* __restrict__ twuT,
    const ushort* __restrict__ vwgT, const ushort* __restrict__ vwuT,
    const float* __restrict__ comb_t, const float* __restrict__ comb_v,
    ushort* __restrict__ H) {
  __shared__ ushort lA[128 * 64];
  __shared__ ushort lBg[64 * 64];
  __shared__ ushort lBu[64 * 64];

  int bid = blockIdx.x;
  int mt  = bid & 7;
  int ntg = bid >> 3;          // 0..111
  int t0  = mt * 128;
  const ushort *Bg, *Bu;
  const float* combp = nullptr;
  int hcol;
  if (ntg < 16) {              // shared experts, F=1024
    int nl = ntg * 64;
    Bg = swgT + (size_t)nl * DIM; Bu = swuT + (size_t)nl * DIM;
    hcol = nl;
  } else if (ntg < 80) {       // text experts, F=512
    int tI = ntg - 16; int e = tI >> 3; int nl = (tI & 7) * 64;
    size_t off = ((size_t)e * 512 + nl) * DIM;
    Bg = twgT + off; Bu = twuT + off;
    combp = comb_t + e;
    hcol = 1024 + e * 512 + nl;
  } else {                     // vision experts, F=256
    int vI = ntg - 80; int e = vI >> 2; int nl = (vI & 3) * 64;
    size_t off = ((size_t)e * 256 + nl) * DIM;
    Bg = vwgT + off; Bu = vwuT + off;
    combp = comb_v + e;
    hcol = 5120 + e * 256 + nl;
  }

  int tid = threadIdx.x;
  int lane = tid & 63, w = tid >> 6;
  int wm = w >> 1, wn = w & 1;
  int fr = lane & 15, fq = lane >> 4;
  int l8 = lane >> 3, l7 = lane & 7;

  f32x4 accg[4][2] = {}; f32x4 accu[4][2] = {};

  for (int k0 = 0; k0 < DIM; k0 += 64) {
    if (k0) __syncthreads();           // prior reads done before overwrite
#pragma unroll
    for (int i = 0; i < 4; ++i) {      // A: 16 chunks of 1KB, 4/wave
      int c = w * 4 + i; int row = c * 8 + l8;
      gld16(Xb + (size_t)(t0 + row) * DIM + k0 + l7 * 8, lA + c * 512);
    }
#pragma unroll
    for (int i = 0; i < 2; ++i) {      // Bg,Bu: 8 chunks each, 2/wave
      int c = w * 2 + i; int row = c * 8 + l8;
      gld16(Bg + (size_t)row * DIM + k0 + l7 * 8, lBg + c * 512);
      gld16(Bu + (size_t)row * DIM + k0 + l7 * 8, lBu + c * 512);
    }
    __syncthreads();                   // vmcnt(0) drain + barrier
#pragma unroll
    for (int kk = 0; kk < 2; ++kk) {
      int kb = kk * 32 + fq * 8;
      bf16x8 a[4], bg[2], bu[2];
#pragma unroll
      for (int m = 0; m < 4; ++m)
        a[m] = *(const bf16x8*)&lA[(wm * 64 + m * 16 + fr) * 64 + kb];
#pragma unroll
      for (int n = 0; n < 2; ++n) {
        bg[n] = *(const bf16x8*)&lBg[(wn * 32 + n * 16 + fr) * 64 + kb];
        bu[n] = *(const bf16x8*)&lBu[(wn * 32 + n * 16 + fr) * 64 + kb];
      }
#pragma unroll
      for (int m = 0; m < 4; ++m)
#pragma unroll
        for (int n = 0; n < 2; ++n) {
          accg[m][n] = __builtin_amdgcn_mfma_f32_16x16x32_bf16(a[m], bg[n], accg[m][n], 0, 0, 0);
          accu[m][n] = __builtin_amdgcn_mfma_f32_16x16x32_bf16(a[m], bu[n], accu[m][n], 0, 0, 0);
        }
    }
  }

#pragma unroll
  for (int m = 0; m < 4; ++m) {
    int tb = t0 + wm * 64 + m * 16 + fq * 4;
    float cv[4];
#pragma unroll
    for (int r = 0; r < 4; ++r)
      cv[r] = combp ? combp[(size_t)(tb + r) * 8] : 1.0f;
#pragma unroll
    for (int n = 0; n < 2; ++n) {
      int col = hcol + wn * 32 + n * 16 + fr;
#pragma unroll
      for (int r = 0; r < 4; ++r) {
        float g = accg[m][n][r], u = accu[m][n][r];
        float h = g / (1.f + __expf(-g)) * u * cv[r];
        H[(size_t)(tb + r) * KCAT + col] = f2bf(h);
      }
    }
  }
}

// ---------------------------------------------------------------------------
// Phase B: partial[sp] = H[:, sp*1024:(sp+1)*1024] @ Wd_seg
// BM=BN=128, BK=64; global_load_lds staging; 4 waves 2x2, wave tile 64x64.
// grid = 8 mt * 8 nt * 7 splits = 448 blocks.
// ---------------------------------------------------------------------------
__global__ __launch_bounds__(256) void moe_down_kernel(
    const ushort* __restrict__ H,
    const ushort* __restrict__ swdT, const ushort* __restrict__ twdT,
    const ushort* __restrict__ vwdT,
    float* __restrict__ part) {
  __shared__ ushort lA[128 * 64];
  __shared__ ushort lB[128 * 64];
  int bid = blockIdx.x;
  int mt = bid & 7, nt = (bid >> 3) & 7, sp = bid >> 6;
  int t0 = mt * 128, n0 = nt * 128;
  int kbeg = sp * KSPL;

  int tid = threadIdx.x;
  int lane = tid & 63, w = tid >> 6;
  int wm = w >> 1, wn = w & 1;
  int fr = lane & 15, fq = lane >> 4;
  int l8 = lane >> 3, l7 = lane & 7;

  f32x4 acc[4][4] = {};

  for (int ks = 0; ks < KSPL; ks += 64) {
    int k0 = kbeg + ks;
    const ushort* Bp; int bs;
    if (k0 < 1024)      { Bp = swdT + k0; bs = 1024; }
    else if (k0 < 5120) { int e = (k0 - 1024) >> 9;
                          Bp = twdT + (size_t)e * DIM * 512 + ((k0 - 1024) & 511); bs = 512; }
    else                { int e = (k0 - 5120) >> 8;
                          Bp = vwdT + (size_t)e * DIM * 256 + ((k0 - 5120) & 255); bs = 256; }
    if (ks) __syncthreads();
#pragma unroll
    for (int i = 0; i < 4; ++i) {      // A + B: 16 chunks each, 4/wave
      int c = w * 4 + i; int row = c * 8 + l8;
      gld16(H + (size_t)(t0 + row) * KCAT + k0 + l7 * 8, lA + c * 512);
      gld16(Bp + (size_t)(n0 + row) * bs + l7 * 8, lB + c * 512);
    }
    __syncthreads();
#pragma unroll
    for (int kk = 0; kk < 2; ++kk) {
      int kb = kk * 32 + fq * 8;
      bf16x8 a[4], b[4];
#pragma unroll
      for (int m = 0; m < 4; ++m)
        a[m] = *(const bf16x8*)&lA[(wm * 64 + m * 16 + fr) * 64 + kb];
#pragma unroll
      for (int n = 0; n < 4; ++n)
        b[n] = *(const bf16x8*)&lB[(wn * 64 + n * 16 + fr) * 64 + kb];
#pragma unroll
      for (int m = 0; m < 4; ++m)
#pragma unroll
        for (int n = 0; n < 4; ++n)
          acc[m][n] = __builtin_amdgcn_mfma_f32_16x16x32_bf16(a[m], b[n], acc[m][n], 0, 0, 0);
    }
  }

  float* pout = part + (size_t)sp * DIM * DIM;
#pragma unroll
  for (int m = 0; m < 4; ++m)
#pragma unroll
    for (int n = 0; n < 4; ++n)
#pragma unroll
      for (int r = 0; r < 4; ++r)
        pout[(size_t)(t0 + wm * 64 + m * 16 + fq * 4 + r) * DIM
             + n0 + wn * 64 + n * 16 + fr] = acc[m][n][r];
}

// ---------------------------------------------------------------------------
// Reduce 7 partials -> out
// ---------------------------------------------------------------------------
__global__ __launch_bounds__(256) void reduce_kernel(
    const float* __restrict__ part, float* __restrict__ out) {
  size_t i = ((size_t)blockIdx.x * 256 + threadIdx.x) * 4;
  f32x4 s = *(const f32x4*)(part + i);
#pragma unroll
  for (int sp = 1; sp < NSPLIT; ++sp) {
    f32x4 v = *(const f32x4*)(part + (size_t)sp * DIM * DIM + i);
    s += v;
  }
  *(f32x4*)(out + i) = s;
}

// ---------------------------------------------------------------------------
extern "C" void kernel_launch(void* const* d_in, const int* in_sizes, int n_in,
                              void* d_out, int out_size, void* d_ws, size_t ws_size,
                              hipStream_t stream) {
  const float* x    = (const float*)d_in[0];
  const int*   tt   = (const int*)d_in[1];
  const float* t_rw = (const float*)d_in[2];
  const float* t_b  = (const float*)d_in[3];
  const float* t_wg = (const float*)d_in[4];
  const float* t_wu = (const float*)d_in[5];
  const float* t_wd = (const float*)d_in[6];
  const float* v_rw = (const float*)d_in[7];
  const float* v_b  = (const float*)d_in[8];
  const float* v_wg = (const float*)d_in[9];
  const float* v_wu = (const float*)d_in[10];
  const float* v_wd = (const float*)d_in[11];
  const float* s_wg = (const float*)d_in[12];
  const float* s_wu = (const float*)d_in[13];
  const float* s_wd = (const float*)d_in[14];
  float* out    = (float*)d_out;
  float* logits = out + (size_t)1024 * 1024;

  char* p = (char*)d_ws;
  auto alloc = [&](size_t bytes) {
    char* r = p; p += (bytes + 255) & ~(size_t)255; return r;
  };
  // buffers live during moe_down:
  ushort* xb     = (ushort*)alloc((size_t)1024 * 1024 * 2);
  float*  comb_t = (float*)alloc((size_t)1024 * 8 * 4);
  float*  comb_v = (float*)alloc((size_t)1024 * 8 * 4);
  ushort* swdT   = (ushort*)alloc((size_t)1024 * 1024 * 2);
  ushort* twdT   = (ushort*)alloc((size_t)8 * 1024 * 512 * 2);
  ushort* vwdT   = (ushort*)alloc((size_t)8 * 1024 * 256 * 2);
  ushort* H      = (ushort*)alloc((size_t)1024 * KCAT * 2);
  // up-only weight buffers (28MB); the 28MB fp32 partials alias this region
  // (up weights are dead once moe_up completes, before moe_down launches).
  char* upmark = p;
  ushort* swgT   = (ushort*)alloc((size_t)1024 * 1024 * 2);
  ushort* swuT   = (ushort*)alloc((size_t)1024 * 1024 * 2);
  ushort* twgT   = (ushort*)alloc((size_t)8 * 512 * 1024 * 2);
  ushort* twuT   = (ushort*)alloc((size_t)8 * 512 * 1024 * 2);
  ushort* vwgT   = (ushort*)alloc((size_t)8 * 256 * 1024 * 2);
  ushort* vwuT   = (ushort*)alloc((size_t)8 * 256 * 1024 * 2);
  float* part = (float*)upmark;        // NSPLIT * 4MB = 28MB, aliases the above

  prep_kernel<<<21504, 256, 0, stream>>>(s_wg, s_wu, s_wd, t_wg, t_wu, t_wd,
                                         v_wg, v_wu, v_wd,
                                         swgT, swuT, swdT, twgT, twuT, twdT,
                                         vwgT, vwuT, vwdT);
  router_kernel<<<256, 256, 0, stream>>>(x, tt, t_rw, t_b, v_rw, v_b,
                                         comb_t, comb_v, logits, xb);
  moe_up_kernel<<<896, 256, 0, stream>>>(xb, swgT, swuT, twgT, twuT, vwgT, vwuT,
                                         comb_t, comb_v, H);
  moe_down_kernel<<<448, 256, 0, stream>>>(H, swdT, twdT, vwdT, part);
  reduce_kernel<<<1024, 256, 0, stream>>>(part, out);
}

// Round 3
// 112.670 us; speedup vs baseline: 2.3142x; 1.0242x over previous
//
#include <hip/hip_runtime.h>

typedef short bf16x8 __attribute__((ext_vector_type(8)));
typedef float f32x4 __attribute__((ext_vector_type(4)));

#define DIM 1024
#define MAXSLOT 4096

__device__ __forceinline__ ushort f2bf(float f) {
  unsigned u = __float_as_uint(f);
  u += 0x7fffu + ((u >> 16) & 1u);   // round-to-nearest-even
  return (ushort)(u >> 16);
}

__device__ __forceinline__ void gld16(const ushort* g, ushort* l) {
  __builtin_amdgcn_global_load_lds(
      (const __attribute__((address_space(1))) unsigned int*)g,
      (__attribute__((address_space(3))) unsigned int*)l, 16, 0, 0);
}

// meta layout (ints): [0..15] cnt (text e0-7, vis e0-7); [16..23] base_text;
// [24] padtot_text; [25..32] base_vis; [33] padtot_vis; [34] ntiles_text;
// [35] ntiles_vis; [40..71] tile_expert_text; [72..103] tile_expert_vis.

// ---------------------------------------------------------------------------
// Weight prep: fp32 [R][C] (batched) -> bf16 [C][R], all 9 tensors, 1 launch.
// Block 0 also zeroes the expert counters.
// ---------------------------------------------------------------------------
__global__ __launch_bounds__(256) void prep_kernel(
    const float* __restrict__ s_wg, const float* __restrict__ s_wu,
    const float* __restrict__ s_wd,
    const float* __restrict__ t_wg, const float* __restrict__ t_wu,
    const float* __restrict__ t_wd,
    const float* __restrict__ v_wg, const float* __restrict__ v_wu,
    const float* __restrict__ v_wd,
    ushort* __restrict__ swgT, ushort* __restrict__ swuT,
    ushort* __restrict__ swdT,
    ushort* __restrict__ twgT, ushort* __restrict__ twuT,
    ushort* __restrict__ twdT,
    ushort* __restrict__ vwgT, ushort* __restrict__ vwuT,
    ushort* __restrict__ vwdT, int* __restrict__ meta) {
  int b = blockIdx.x;
  if (b == 0 && threadIdx.x < 16) meta[threadIdx.x] = 0;
  const float* src; ushort* dst; int R, C;
  if (b < 3072) {
    int t = b >> 10; b &= 1023;
    src = t == 0 ? s_wg : (t == 1 ? s_wu : s_wd);
    dst = t == 0 ? swgT : (t == 1 ? swuT : swdT);
    R = 1024; C = 1024;
  } else if (b < 11264) {
    b -= 3072; int t = b >> 12; b &= 4095;
    src = t == 0 ? t_wg : t_wu; dst = t == 0 ? twgT : twuT;
    R = 1024; C = 512;
  } else if (b < 15360) {
    b -= 11264; src = t_wd; dst = twdT; R = 512; C = 1024;
  } else if (b < 19456) {
    b -= 15360; int t = b >> 11; b &= 2047;
    src = t == 0 ? v_wg : v_wu; dst = t == 0 ? vwgT : vwuT;
    R = 1024; C = 256;
  } else {
    b -= 19456; src = v_wd; dst = vwdT; R = 256; C = 1024;
  }
  int tilesC = C >> 5, tilesR = R >> 5;
  int per = tilesR * tilesC;
  int z = b / per; int rem = b - z * per;
  int r0 = (rem / tilesC) << 5, c0 = (rem - (rem / tilesC) * tilesC) << 5;
  size_t boff = (size_t)z * R * C;
  src += boff; dst += boff;
  __shared__ float tile[32][33];
  int tx = threadIdx.x & 31, ty = threadIdx.x >> 5;
#pragma unroll
  for (int i = 0; i < 32; i += 8)
    tile[ty + i][tx] = src[(size_t)(r0 + ty + i) * C + c0 + tx];
  __syncthreads();
#pragma unroll
  for (int i = 0; i < 32; i += 8)
    dst[(size_t)(c0 + ty + i) * R + r0 + tx] = f2bf(tile[tx][ty + i]);
}

// ---------------------------------------------------------------------------
// Router: logits (token's modality), softmax, biased top-2, normalized
// weights; assigns per-expert ranks via atomics; writes logits + bf16 X.
// ---------------------------------------------------------------------------
__global__ __launch_bounds__(256) void router_kernel(
    const float* __restrict__ x, const int* __restrict__ tt,
    const float* __restrict__ t_rw, const float* __restrict__ t_bias,
    const float* __restrict__ v_rw, const float* __restrict__ v_bias,
    int* __restrict__ meta, int4* __restrict__ ti, float2* __restrict__ tw,
    float* __restrict__ logits_out, ushort* __restrict__ xb) {
  int t = blockIdx.x * 4 + (threadIdx.x >> 6);
  int lane = threadIdx.x & 63;
  const float* xr = x + (size_t)t * DIM;
  int vis = tt[t] != 0;
  const float* rw   = vis ? v_rw   : t_rw;
  const float* bias = vis ? v_bias : t_bias;
  float xv[16];
#pragma unroll
  for (int i = 0; i < 16; ++i) {
    float v = xr[lane + 64 * i];
    xv[i] = v;
    xb[(size_t)t * DIM + lane + 64 * i] = f2bf(v);
  }
  float lg[8];
#pragma unroll
  for (int e = 0; e < 8; ++e) {
    const float* wrow = rw + (size_t)e * DIM;
    float s = 0.f;
#pragma unroll
    for (int i = 0; i < 16; ++i) s += xv[i] * wrow[lane + 64 * i];
#pragma unroll
    for (int off = 32; off > 0; off >>= 1) s += __shfl_xor(s, off);
    lg[e] = s;
  }
  if (lane == 0) {
    float mx = lg[0];
    for (int e = 1; e < 8; ++e) mx = fmaxf(mx, lg[e]);
    float ex[8]; float sum = 0.f;
    for (int e = 0; e < 8; ++e) { ex[e] = __expf(lg[e] - mx); sum += ex[e]; }
    float inv = 1.f / sum;
    float pr[8], sc[8];
    for (int e = 0; e < 8; ++e) { pr[e] = ex[e] * inv; sc[e] = pr[e] + bias[e]; }
    int i0 = 0;
    for (int e = 1; e < 8; ++e) if (sc[e] > sc[i0]) i0 = e;
    int i1 = -1;
    for (int e = 0; e < 8; ++e) {
      if (e == i0) continue;
      if (i1 < 0 || sc[e] > sc[i1]) i1 = e;
    }
    float w0 = pr[i0], w1 = pr[i1];
    float s2 = fmaxf(w0 + w1, 1e-12f);
    w0 /= s2; w1 /= s2;
    int r0 = atomicAdd(&meta[vis * 8 + i0], 1);
    int r1 = atomicAdd(&meta[vis * 8 + i1], 1);
    ti[t] = make_int4(i0 | (vis << 8), r0, i1, r1);
    tw[t] = make_float2(w0, w1);
    for (int e = 0; e < 8; ++e) logits_out[(size_t)t * 8 + e] = lg[e];
  }
}

// ---------------------------------------------------------------------------
// Finalize: padded bases, tile->expert maps, slot->token lists. One block.
// ---------------------------------------------------------------------------
__global__ __launch_bounds__(256) void finalize_kernel(
    int* __restrict__ meta, const int4* __restrict__ ti,
    int* __restrict__ tok_text, int* __restrict__ tok_vis) {
  __shared__ int sb[16];
  if (threadIdx.x == 0) {
    int bt = 0, tc = 0;
    for (int e = 0; e < 8; ++e) {
      sb[e] = bt; meta[16 + e] = bt;
      int nt = (meta[e] + 127) >> 7;
      for (int i = 0; i < nt; ++i) meta[40 + tc++] = e;
      bt += nt << 7;
    }
    meta[24] = bt; meta[34] = bt >> 7;
    int bv = 0, vc = 0;
    for (int e = 0; e < 8; ++e) {
      sb[8 + e] = bv; meta[25 + e] = bv;
      int nt = (meta[8 + e] + 127) >> 7;
      for (int i = 0; i < nt; ++i) meta[72 + vc++] = e;
      bv += nt << 7;
    }
    meta[33] = bv; meta[35] = bv >> 7;
  }
  __syncthreads();
  for (int i = threadIdx.x; i < MAXSLOT; i += 256) { tok_text[i] = 0; tok_vis[i] = 0; }
  __syncthreads();
  for (int t = threadIdx.x; t < 1024; t += 256) {
    int4 v = ti[t];
    int e0 = v.x & 0xff, vis = v.x >> 8, e1 = v.z;
    int* tl = vis ? tok_vis : tok_text;
    tl[sb[vis * 8 + e0] + v.y] = t;
    tl[sb[vis * 8 + e1] + v.w] = t;
  }
}

// ---------------------------------------------------------------------------
// Up: H = silu(Xg @ Wg) * (Xg @ Wu). 3 sections: shared / text / vision.
// BM=128, BN=64, BK=64; gathered A rows; global_load_lds staging.
// grid = 128 (shared) + 256 (text) + 128 (vis) = 512.
// ---------------------------------------------------------------------------
__global__ __launch_bounds__(256) void up_kernel(
    const ushort* __restrict__ Xb,
    const ushort* __restrict__ swgT, const ushort* __restrict__ swuT,
    const ushort* __restrict__ twgT, const ushort* __restrict__ twuT,
    const ushort* __restrict__ vwgT, const ushort* __restrict__ vwuT,
    const int* __restrict__ meta,
    const int* __restrict__ tok_text, const int* __restrict__ tok_vis,
    ushort* __restrict__ H_sh, ushort* __restrict__ H_tx,
    ushort* __restrict__ H_vs) {
  __shared__ ushort lA[128 * 64];
  __shared__ ushort lBg[64 * 64];
  __shared__ ushort lBu[64 * 64];
  int b = blockIdx.x;
  int tid = threadIdx.x, lane = tid & 63, w = tid >> 6;
  int wm = w >> 1, wn = w & 1;
  int fr = lane & 15, fq = lane >> 4;
  int l8 = lane >> 3, l7 = lane & 7;

  const ushort *Bg, *Bu;
  const int* tl = nullptr;
  ushort* Hout; int hstride, t0, ncol0;
  if (b < 128) {                       // shared experts
    int mt = b >> 4, ng = b & 15;
    t0 = mt * 128; ncol0 = ng * 64;
    Bg = swgT + (size_t)ncol0 * DIM; Bu = swuT + (size_t)ncol0 * DIM;
    Hout = H_sh; hstride = 1024;
  } else if (b < 384) {                // text experts
    int rel = b - 128; int mt = rel >> 3, ng = rel & 7;
    if (mt >= meta[34]) return;
    int e = meta[40 + mt];
    t0 = mt * 128; ncol0 = ng * 64;
    size_t off = ((size_t)e * 512 + ncol0) * DIM;
    Bg = twgT + off; Bu = twuT + off;
    tl = tok_text; Hout = H_tx; hstride = 512;
  } else {                             // vision experts
    int rel = b - 384; int mt = rel >> 2, ng = rel & 3;
    if (mt >= meta[35]) return;
    int e = meta[72 + mt];
    t0 = mt * 128; ncol0 = ng * 64;
    size_t off = ((size_t)e * 256 + ncol0) * DIM;
    Bg = vwgT + off; Bu = vwuT + off;
    tl = tok_vis; Hout = H_vs; hstride = 256;
  }

  const ushort* aptr[4];
#pragma unroll
  for (int i = 0; i < 4; ++i) {
    int row = (w * 4 + i) * 8 + l8;
    int tok = tl ? tl[t0 + row] : (t0 + row);
    aptr[i] = Xb + (size_t)tok * DIM + l7 * 8;
  }
  const ushort *bgp[2], *bup[2];
#pragma unroll
  for (int i = 0; i < 2; ++i) {
    int row = (w * 2 + i) * 8 + l8;
    bgp[i] = Bg + (size_t)row * DIM + l7 * 8;
    bup[i] = Bu + (size_t)row * DIM + l7 * 8;
  }

  f32x4 accg[4][2] = {}; f32x4 accu[4][2] = {};

  for (int k0 = 0; k0 < DIM; k0 += 64) {
    if (k0) __syncthreads();
#pragma unroll
    for (int i = 0; i < 4; ++i)
      gld16(aptr[i] + k0, lA + (w * 4 + i) * 512);
#pragma unroll
    for (int i = 0; i < 2; ++i) {
      gld16(bgp[i] + k0, lBg + (w * 2 + i) * 512);
      gld16(bup[i] + k0, lBu + (w * 2 + i) * 512);
    }
    __syncthreads();
#pragma unroll
    for (int kk = 0; kk < 2; ++kk) {
      int kb = kk * 32 + fq * 8;
      bf16x8 a[4], bg[2], bu[2];
#pragma unroll
      for (int m = 0; m < 4; ++m)
        a[m] = *(const bf16x8*)&lA[(wm * 64 + m * 16 + fr) * 64 + kb];
#pragma unroll
      for (int n = 0; n < 2; ++n) {
        bg[n] = *(const bf16x8*)&lBg[(wn * 32 + n * 16 + fr) * 64 + kb];
        bu[n] = *(const bf16x8*)&lBu[(wn * 32 + n * 16 + fr) * 64 + kb];
      }
#pragma unroll
      for (int m = 0; m < 4; ++m)
#pragma unroll
        for (int n = 0; n < 2; ++n) {
          accg[m][n] = __builtin_amdgcn_mfma_f32_16x16x32_bf16(a[m], bg[n], accg[m][n], 0, 0, 0);
          accu[m][n] = __builtin_amdgcn_mfma_f32_16x16x32_bf16(a[m], bu[n], accu[m][n], 0, 0, 0);
        }
    }
  }

#pragma unroll
  for (int m = 0; m < 4; ++m) {
    int rb = t0 + wm * 64 + m * 16 + fq * 4;
#pragma unroll
    for (int n = 0; n < 2; ++n) {
      int col = ncol0 + wn * 32 + n * 16 + fr;
#pragma unroll
      for (int r = 0; r < 4; ++r) {
        float g = accg[m][n][r], u = accu[m][n][r];
        float h = g / (1.f + __expf(-g)) * u;
        Hout[(size_t)(rb + r) * hstride + col] = f2bf(h);
      }
    }
  }
}

// ---------------------------------------------------------------------------
// Down: shared -> out directly; routed -> per-pair fp32 rows pd[slot][1024].
// BM=BN=128, BK=64. grid = 64 (shared) + 256 (text) + 256 (vis) = 576.
// ---------------------------------------------------------------------------
__global__ __launch_bounds__(256) void down_kernel(
    const ushort* __restrict__ H_sh, const ushort* __restrict__ H_tx,
    const ushort* __restrict__ H_vs,
    const ushort* __restrict__ swdT, const ushort* __restrict__ twdT,
    const ushort* __restrict__ vwdT,
    const int* __restrict__ meta, float* __restrict__ out,
    float* __restrict__ pd_tx, float* __restrict__ pd_vs) {
  __shared__ ushort lA[128 * 64];
  __shared__ ushort lB[128 * 64];
  int b = blockIdx.x;
  int tid = threadIdx.x, lane = tid & 63, w = tid >> 6;
  int wm = w >> 1, wn = w & 1;
  int fr = lane & 15, fq = lane >> 4;
  int l8 = lane >> 3, l7 = lane & 7;

  const ushort *A, *B; float* O;
  int ksteps, astride, bstride, t0, n0;
  if (b < 64) {                        // shared
    int mt = b >> 3, nt = b & 7;
    t0 = mt * 128; n0 = nt * 128;
    A = H_sh; astride = 1024; B = swdT; bstride = 1024; ksteps = 16;
    O = out;
  } else if (b < 320) {                // text
    int rel = b - 64; int mt = rel >> 3, nt = rel & 7;
    if (mt >= meta[34]) return;
    int e = meta[40 + mt];
    t0 = mt * 128; n0 = nt * 128;
    A = H_tx; astride = 512;
    B = twdT + (size_t)e * 1024 * 512; bstride = 512; ksteps = 8;
    O = pd_tx;
  } else {                             // vision
    int rel = b - 320; int mt = rel >> 3, nt = rel & 7;
    if (mt >= meta[35]) return;
    int e = meta[72 + mt];
    t0 = mt * 128; n0 = nt * 128;
    A = H_vs; astride = 256;
    B = vwdT + (size_t)e * 1024 * 256; bstride = 256; ksteps = 4;
    O = pd_vs;
  }

  const ushort *aptr[4], *bptr[4];
#pragma unroll
  for (int i = 0; i < 4; ++i) {
    int row = (w * 4 + i) * 8 + l8;
    aptr[i] = A + (size_t)(t0 + row) * astride + l7 * 8;
    bptr[i] = B + (size_t)(n0 + row) * bstride + l7 * 8;
  }

  f32x4 acc[4][4] = {};
  int kend = ksteps * 64;
  for (int k0 = 0; k0 < kend; k0 += 64) {
    if (k0) __syncthreads();
#pragma unroll
    for (int i = 0; i < 4; ++i) {
      gld16(aptr[i] + k0, lA + (w * 4 + i) * 512);
      gld16(bptr[i] + k0, lB + (w * 4 + i) * 512);
    }
    __syncthreads();
#pragma unroll
    for (int kk = 0; kk < 2; ++kk) {
      int kb = kk * 32 + fq * 8;
      bf16x8 a[4], bb[4];
#pragma unroll
      for (int m = 0; m < 4; ++m)
        a[m] = *(const bf16x8*)&lA[(wm * 64 + m * 16 + fr) * 64 + kb];
#pragma unroll
      for (int n = 0; n < 4; ++n)
        bb[n] = *(const bf16x8*)&lB[(wn * 64 + n * 16 + fr) * 64 + kb];
#pragma unroll
      for (int m = 0; m < 4; ++m)
#pragma unroll
        for (int n = 0; n < 4; ++n)
          acc[m][n] = __builtin_amdgcn_mfma_f32_16x16x32_bf16(a[m], bb[n], acc[m][n], 0, 0, 0);
    }
  }

#pragma unroll
  for (int m = 0; m < 4; ++m)
#pragma unroll
    for (int n = 0; n < 4; ++n)
#pragma unroll
      for (int r = 0; r < 4; ++r)
        O[(size_t)(t0 + wm * 64 + m * 16 + fq * 4 + r) * DIM
          + n0 + wn * 64 + n * 16 + fr] = acc[m][n][r];
}

// ---------------------------------------------------------------------------
// Combine: out[t] += w0 * pd[slot0] + w1 * pd[slot1]
// ---------------------------------------------------------------------------
__global__ __launch_bounds__(256) void combine_kernel(
    const int4* __restrict__ ti, const float2* __restrict__ tw,
    const int* __restrict__ meta,
    const float* __restrict__ pd_tx, const float* __restrict__ pd_vs,
    float* __restrict__ out) {
  int t = blockIdx.x;
  int4 v = ti[t]; float2 wv = tw[t];
  int e0 = v.x & 0xff, vis = v.x >> 8, e1 = v.z;
  const int* base = meta + (vis ? 25 : 16);
  const float* pd = vis ? pd_vs : pd_tx;
  size_t s0 = base[e0] + v.y, s1 = base[e1] + v.w;
  int d = threadIdx.x * 4;
  f32x4 a  = *(const f32x4*)(out + (size_t)t * DIM + d);
  f32x4 p0 = *(const f32x4*)(pd + s0 * DIM + d);
  f32x4 p1 = *(const f32x4*)(pd + s1 * DIM + d);
#pragma unroll
  for (int j = 0; j < 4; ++j) a[j] = a[j] + wv.x * p0[j] + wv.y * p1[j];
  *(f32x4*)(out + (size_t)t * DIM + d) = a;
}

// ---------------------------------------------------------------------------
extern "C" void kernel_launch(void* const* d_in, const int* in_sizes, int n_in,
                              void* d_out, int out_size, void* d_ws, size_t ws_size,
                              hipStream_t stream) {
  const float* x    = (const float*)d_in[0];
  const int*   tt   = (const int*)d_in[1];
  const float* t_rw = (const float*)d_in[2];
  const float* t_b  = (const float*)d_in[3];
  const float* t_wg = (const float*)d_in[4];
  const float* t_wu = (const float*)d_in[5];
  const float* t_wd = (const float*)d_in[6];
  const float* v_rw = (const float*)d_in[7];
  const float* v_b  = (const float*)d_in[8];
  const float* v_wg = (const float*)d_in[9];
  const float* v_wu = (const float*)d_in[10];
  const float* v_wd = (const float*)d_in[11];
  const float* s_wg = (const float*)d_in[12];
  const float* s_wu = (const float*)d_in[13];
  const float* s_wd = (const float*)d_in[14];
  float* out    = (float*)d_out;
  float* logits = out + (size_t)1024 * 1024;

  char* p = (char*)d_ws;
  auto alloc = [&](size_t bytes) {
    char* r = p; p += (bytes + 255) & ~(size_t)255; return r;
  };
  ushort* xb     = (ushort*)alloc((size_t)1024 * 1024 * 2);
  int4*   ti     = (int4*)alloc((size_t)1024 * 16);
  float2* tw     = (float2*)alloc((size_t)1024 * 8);
  int*    meta   = (int*)alloc(512 * 4);
  int*    tok_tx = (int*)alloc(MAXSLOT * 4);
  int*    tok_vs = (int*)alloc(MAXSLOT * 4);
  ushort* swdT   = (ushort*)alloc((size_t)1024 * 1024 * 2);
  ushort* twdT   = (ushort*)alloc((size_t)8 * 1024 * 512 * 2);
  ushort* vwdT   = (ushort*)alloc((size_t)8 * 1024 * 256 * 2);
  ushort* H_sh   = (ushort*)alloc((size_t)1024 * 1024 * 2);
  ushort* H_tx   = (ushort*)alloc((size_t)MAXSLOT * 512 * 2);
  ushort* H_vs   = (ushort*)alloc((size_t)MAXSLOT * 256 * 2);
  // union region: up-only weights (28MB) overlaid later by pd buffers (32MB)
  char* upmark = p;
  ushort* swgT   = (ushort*)alloc((size_t)1024 * 1024 * 2);
  ushort* swuT   = (ushort*)alloc((size_t)1024 * 1024 * 2);
  ushort* twgT   = (ushort*)alloc((size_t)8 * 512 * 1024 * 2);
  ushort* twuT   = (ushort*)alloc((size_t)8 * 512 * 1024 * 2);
  ushort* vwgT   = (ushort*)alloc((size_t)8 * 256 * 1024 * 2);
  ushort* vwuT   = (ushort*)alloc((size_t)8 * 256 * 1024 * 2);
  float* pd_tx = (float*)upmark;                       // 16 MB
  float* pd_vs = (float*)(upmark + (size_t)MAXSLOT * DIM * 4);  // 16 MB

  prep_kernel<<<21504, 256, 0, stream>>>(s_wg, s_wu, s_wd, t_wg, t_wu, t_wd,
                                         v_wg, v_wu, v_wd,
                                         swgT, swuT, swdT, twgT, twuT, twdT,
                                         vwgT, vwuT, vwdT, meta);
  router_kernel<<<256, 256, 0, stream>>>(x, tt, t_rw, t_b, v_rw, v_b,
                                         meta, ti, tw, logits, xb);
  finalize_kernel<<<1, 256, 0, stream>>>(meta, ti, tok_tx, tok_vs);
  up_kernel<<<512, 256, 0, stream>>>(xb, swgT, swuT, twgT, twuT, vwgT, vwuT,
                                     meta, tok_tx, tok_vs, H_sh, H_tx, H_vs);
  down_kernel<<<576, 256, 0, stream>>>(H_sh, H_tx, H_vs, swdT, twdT, vwdT,
                                       meta, out, pd_tx, pd_vs);
  combine_kernel<<<1024, 256, 0, stream>>>(ti, tw, meta, pd_tx, pd_vs, out);
}

// Round 4
// 96.116 us; speedup vs baseline: 2.7128x; 1.1722x over previous
//
#include <hip/hip_runtime.h>

typedef short bf16x8 __attribute__((ext_vector_type(8)));
typedef float f32x4 __attribute__((ext_vector_type(4)));

#define DIM 1024
#define MAXSLOT 4096
#define PREP_BLOCKS 21504

__device__ __forceinline__ ushort f2bf(float f) {
  unsigned u = __float_as_uint(f);
  u += 0x7fffu + ((u >> 16) & 1u);   // round-to-nearest-even
  return (ushort)(u >> 16);
}

__device__ __forceinline__ void gld16(const ushort* g, ushort* l) {
  __builtin_amdgcn_global_load_lds(
      (const __attribute__((address_space(1))) unsigned int*)g,
      (__attribute__((address_space(3))) unsigned int*)l, 16, 0, 0);
}

// meta layout (ints): [16..23] base_text; [25..32] base_vis; [34] ntiles_text;
// [35] ntiles_vis; [40..71] tile_expert_text; [72..103] tile_expert_vis.

// ---------------------------------------------------------------------------
// Fused: blocks [0,21504): weight transpose fp32 [R][C] -> bf16 [C][R].
//        blocks [21504,21760): router (no atomics; rank assigned in finalize).
// ---------------------------------------------------------------------------
__global__ __launch_bounds__(256) void prep_router_kernel(
    const float* __restrict__ s_wg, const float* __restrict__ s_wu,
    const float* __restrict__ s_wd,
    const float* __restrict__ t_wg, const float* __restrict__ t_wu,
    const float* __restrict__ t_wd,
    const float* __restrict__ v_wg, const float* __restrict__ v_wu,
    const float* __restrict__ v_wd,
    ushort* __restrict__ swgT, ushort* __restrict__ swuT,
    ushort* __restrict__ swdT,
    ushort* __restrict__ twgT, ushort* __restrict__ twuT,
    ushort* __restrict__ twdT,
    ushort* __restrict__ vwgT, ushort* __restrict__ vwuT,
    ushort* __restrict__ vwdT,
    const float* __restrict__ x, const int* __restrict__ tt,
    const float* __restrict__ t_rw, const float* __restrict__ t_bias,
    const float* __restrict__ v_rw, const float* __restrict__ v_bias,
    int4* __restrict__ ti, float2* __restrict__ tw,
    float* __restrict__ logits_out, ushort* __restrict__ xb) {
  int b = blockIdx.x;
  if (b >= PREP_BLOCKS) {
    // ---------------- router role ----------------
    int t = (b - PREP_BLOCKS) * 4 + (threadIdx.x >> 6);
    int lane = threadIdx.x & 63;
    const float* xr = x + (size_t)t * DIM;
    int vis = tt[t] != 0;
    const float* rw   = vis ? v_rw   : t_rw;
    const float* bias = vis ? v_bias : t_bias;
    float4 xv[4];
#pragma unroll
    for (int i = 0; i < 4; ++i) {
      xv[i] = *(const float4*)(xr + lane * 4 + 256 * i);
      ushort4 o;
      o.x = f2bf(xv[i].x); o.y = f2bf(xv[i].y);
      o.z = f2bf(xv[i].z); o.w = f2bf(xv[i].w);
      *(ushort4*)(xb + (size_t)t * DIM + lane * 4 + 256 * i) = o;
    }
    float lg[8];
#pragma unroll
    for (int e = 0; e < 8; ++e) {
      const float* wrow = rw + (size_t)e * DIM;
      float s = 0.f;
#pragma unroll
      for (int i = 0; i < 4; ++i) {
        float4 wv = *(const float4*)(wrow + lane * 4 + 256 * i);
        s += xv[i].x * wv.x + xv[i].y * wv.y + xv[i].z * wv.z + xv[i].w * wv.w;
      }
#pragma unroll
      for (int off = 32; off > 0; off >>= 1) s += __shfl_xor(s, off);
      lg[e] = s;
    }
    if (lane == 0) {
      float mx = lg[0];
      for (int e = 1; e < 8; ++e) mx = fmaxf(mx, lg[e]);
      float ex[8]; float sum = 0.f;
      for (int e = 0; e < 8; ++e) { ex[e] = __expf(lg[e] - mx); sum += ex[e]; }
      float inv = 1.f / sum;
      float pr[8], sc[8];
      for (int e = 0; e < 8; ++e) { pr[e] = ex[e] * inv; sc[e] = pr[e] + bias[e]; }
      int i0 = 0;
      for (int e = 1; e < 8; ++e) if (sc[e] > sc[i0]) i0 = e;
      int i1 = -1;
      for (int e = 0; e < 8; ++e) {
        if (e == i0) continue;
        if (i1 < 0 || sc[e] > sc[i1]) i1 = e;
      }
      float w0 = pr[i0], w1 = pr[i1];
      float s2 = fmaxf(w0 + w1, 1e-12f);
      w0 /= s2; w1 /= s2;
      ti[t] = make_int4(i0 | (vis << 8), 0, i1, 0);
      tw[t] = make_float2(w0, w1);
      for (int e = 0; e < 8; ++e) logits_out[(size_t)t * 8 + e] = lg[e];
    }
    return;
  }
  // ---------------- prep (transpose+convert) role ----------------
  const float* src; ushort* dst; int R, C;
  if (b < 3072) {
    int t = b >> 10; b &= 1023;
    src = t == 0 ? s_wg : (t == 1 ? s_wu : s_wd);
    dst = t == 0 ? swgT : (t == 1 ? swuT : swdT);
    R = 1024; C = 1024;
  } else if (b < 11264) {
    b -= 3072; int t = b >> 12; b &= 4095;
    src = t == 0 ? t_wg : t_wu; dst = t == 0 ? twgT : twuT;
    R = 1024; C = 512;
  } else if (b < 15360) {
    b -= 11264; src = t_wd; dst = twdT; R = 512; C = 1024;
  } else if (b < 19456) {
    b -= 15360; int t = b >> 11; b &= 2047;
    src = t == 0 ? v_wg : v_wu; dst = t == 0 ? vwgT : vwuT;
    R = 1024; C = 256;
  } else {
    b -= 19456; src = v_wd; dst = vwdT; R = 256; C = 1024;
  }
  int tilesC = C >> 5;
  int per = (R >> 5) * tilesC;
  int z = b / per; int rem = b - z * per;
  int r0 = (rem / tilesC) << 5, c0 = (rem - (rem / tilesC) * tilesC) << 5;
  size_t boff = (size_t)z * R * C;
  src += boff; dst += boff;
  __shared__ float tile[32][33];
  int tx = threadIdx.x & 7, ty = threadIdx.x >> 3;      // 8 x 32
  float4 v = *(const float4*)(src + (size_t)(r0 + ty) * C + c0 + tx * 4);
  tile[ty][tx * 4 + 0] = v.x; tile[ty][tx * 4 + 1] = v.y;
  tile[ty][tx * 4 + 2] = v.z; tile[ty][tx * 4 + 3] = v.w;
  __syncthreads();
  ushort4 o;
  o.x = f2bf(tile[tx * 4 + 0][ty]);
  o.y = f2bf(tile[tx * 4 + 1][ty]);
  o.z = f2bf(tile[tx * 4 + 2][ty]);
  o.w = f2bf(tile[tx * 4 + 3][ty]);
  *(ushort4*)(dst + (size_t)(c0 + ty) * R + r0 + tx * 4) = o;
}

// ---------------------------------------------------------------------------
// Finalize: ranks via LDS atomics, padded bases, tile->expert maps,
// slot->token lists. One block.
// ---------------------------------------------------------------------------
__global__ __launch_bounds__(256) void finalize_kernel(
    int* __restrict__ meta, int4* __restrict__ ti,
    int* __restrict__ tok_text, int* __restrict__ tok_vis) {
  __shared__ int cnt[16];
  __shared__ int sb[16];
  if (threadIdx.x < 16) cnt[threadIdx.x] = 0;
  __syncthreads();
  for (int t = threadIdx.x; t < 1024; t += 256) {
    int4 v = ti[t];
    int e0 = v.x & 0xff, vis = v.x >> 8, e1 = v.z;
    v.y = atomicAdd(&cnt[vis * 8 + e0], 1);
    v.w = atomicAdd(&cnt[vis * 8 + e1], 1);
    ti[t] = v;
  }
  __syncthreads();
  if (threadIdx.x == 0) {
    int bt = 0, tc = 0;
    for (int e = 0; e < 8; ++e) {
      sb[e] = bt; meta[16 + e] = bt;
      int nt = (cnt[e] + 127) >> 7;
      for (int i = 0; i < nt; ++i) meta[40 + tc++] = e;
      bt += nt << 7;
    }
    meta[34] = bt >> 7;
    int bv = 0, vc = 0;
    for (int e = 0; e < 8; ++e) {
      sb[8 + e] = bv; meta[25 + e] = bv;
      int nt = (cnt[8 + e] + 127) >> 7;
      for (int i = 0; i < nt; ++i) meta[72 + vc++] = e;
      bv += nt << 7;
    }
    meta[35] = bv >> 7;
  }
  __syncthreads();
  for (int i = threadIdx.x; i < MAXSLOT; i += 256) { tok_text[i] = 0; tok_vis[i] = 0; }
  __syncthreads();
  for (int t = threadIdx.x; t < 1024; t += 256) {
    int4 v = ti[t];
    int e0 = v.x & 0xff, vis = v.x >> 8, e1 = v.z;
    int* tl = vis ? tok_vis : tok_text;
    tl[sb[vis * 8 + e0] + v.y] = t;
    tl[sb[vis * 8 + e1] + v.w] = t;
  }
}

// ---------------------------------------------------------------------------
// Up: H = silu(Xg @ Wg) * (Xg @ Wu). 3 sections: shared / text / vision.
// BM=128, BN=64, BK=64; gathered A rows; global_load_lds staging.
// ---------------------------------------------------------------------------
__global__ __launch_bounds__(256) void up_kernel(
    const ushort* __restrict__ Xb,
    const ushort* __restrict__ swgT, const ushort* __restrict__ swuT,
    const ushort* __restrict__ twgT, const ushort* __restrict__ twuT,
    const ushort* __restrict__ vwgT, const ushort* __restrict__ vwuT,
    const int* __restrict__ meta,
    const int* __restrict__ tok_text, const int* __restrict__ tok_vis,
    ushort* __restrict__ H_sh, ushort* __restrict__ H_tx,
    ushort* __restrict__ H_vs) {
  __shared__ ushort lA[128 * 64];
  __shared__ ushort lBg[64 * 64];
  __shared__ ushort lBu[64 * 64];
  int b = blockIdx.x;
  int tid = threadIdx.x, lane = tid & 63, w = tid >> 6;
  int wm = w >> 1, wn = w & 1;
  int fr = lane & 15, fq = lane >> 4;
  int l8 = lane >> 3, l7 = lane & 7;

  const ushort *Bg, *Bu;
  const int* tl = nullptr;
  ushort* Hout; int hstride, t0, ncol0;
  if (b < 128) {                       // shared experts
    int mt = b >> 4, ng = b & 15;
    t0 = mt * 128; ncol0 = ng * 64;
    Bg = swgT + (size_t)ncol0 * DIM; Bu = swuT + (size_t)ncol0 * DIM;
    Hout = H_sh; hstride = 1024;
  } else if (b < 384) {                // text experts
    int rel = b - 128; int mt = rel >> 3, ng = rel & 7;
    if (mt >= meta[34]) return;
    int e = meta[40 + mt];
    t0 = mt * 128; ncol0 = ng * 64;
    size_t off = ((size_t)e * 512 + ncol0) * DIM;
    Bg = twgT + off; Bu = twuT + off;
    tl = tok_text; Hout = H_tx; hstride = 512;
  } else {                             // vision experts
    int rel = b - 384; int mt = rel >> 2, ng = rel & 3;
    if (mt >= meta[35]) return;
    int e = meta[72 + mt];
    t0 = mt * 128; ncol0 = ng * 64;
    size_t off = ((size_t)e * 256 + ncol0) * DIM;
    Bg = vwgT + off; Bu = vwuT + off;
    tl = tok_vis; Hout = H_vs; hstride = 256;
  }

  const ushort* aptr[4];
#pragma unroll
  for (int i = 0; i < 4; ++i) {
    int row = (w * 4 + i) * 8 + l8;
    int tok = tl ? tl[t0 + row] : (t0 + row);
    aptr[i] = Xb + (size_t)tok * DIM + l7 * 8;
  }
  const ushort *bgp[2], *bup[2];
#pragma unroll
  for (int i = 0; i < 2; ++i) {
    int row = (w * 2 + i) * 8 + l8;
    bgp[i] = Bg + (size_t)row * DIM + l7 * 8;
    bup[i] = Bu + (size_t)row * DIM + l7 * 8;
  }

  f32x4 accg[4][2] = {}; f32x4 accu[4][2] = {};

  for (int k0 = 0; k0 < DIM; k0 += 64) {
    if (k0) __syncthreads();
#pragma unroll
    for (int i = 0; i < 4; ++i)
      gld16(aptr[i] + k0, lA + (w * 4 + i) * 512);
#pragma unroll
    for (int i = 0; i < 2; ++i) {
      gld16(bgp[i] + k0, lBg + (w * 2 + i) * 512);
      gld16(bup[i] + k0, lBu + (w * 2 + i) * 512);
    }
    __syncthreads();
#pragma unroll
    for (int kk = 0; kk < 2; ++kk) {
      int kb = kk * 32 + fq * 8;
      bf16x8 a[4], bg[2], bu[2];
#pragma unroll
      for (int m = 0; m < 4; ++m)
        a[m] = *(const bf16x8*)&lA[(wm * 64 + m * 16 + fr) * 64 + kb];
#pragma unroll
      for (int n = 0; n < 2; ++n) {
        bg[n] = *(const bf16x8*)&lBg[(wn * 32 + n * 16 + fr) * 64 + kb];
        bu[n] = *(const bf16x8*)&lBu[(wn * 32 + n * 16 + fr) * 64 + kb];
      }
#pragma unroll
      for (int m = 0; m < 4; ++m)
#pragma unroll
        for (int n = 0; n < 2; ++n) {
          accg[m][n] = __builtin_amdgcn_mfma_f32_16x16x32_bf16(a[m], bg[n], accg[m][n], 0, 0, 0);
          accu[m][n] = __builtin_amdgcn_mfma_f32_16x16x32_bf16(a[m], bu[n], accu[m][n], 0, 0, 0);
        }
    }
  }

#pragma unroll
  for (int m = 0; m < 4; ++m) {
    int rb = t0 + wm * 64 + m * 16 + fq * 4;
#pragma unroll
    for (int n = 0; n < 2; ++n) {
      int col = ncol0 + wn * 32 + n * 16 + fr;
#pragma unroll
      for (int r = 0; r < 4; ++r) {
        float g = accg[m][n][r], u = accu[m][n][r];
        float h = g / (1.f + __expf(-g)) * u;
        Hout[(size_t)(rb + r) * hstride + col] = f2bf(h);
      }
    }
  }
}

// ---------------------------------------------------------------------------
// Down: shared -> out directly; routed -> per-pair fp32 rows pd[slot][1024].
// BM=BN=128, BK=64.
// ---------------------------------------------------------------------------
__global__ __launch_bounds__(256) void down_kernel(
    const ushort* __restrict__ H_sh, const ushort* __restrict__ H_tx,
    const ushort* __restrict__ H_vs,
    const ushort* __restrict__ swdT, const ushort* __restrict__ twdT,
    const ushort* __restrict__ vwdT,
    const int* __restrict__ meta, float* __restrict__ out,
    float* __restrict__ pd_tx, float* __restrict__ pd_vs) {
  __shared__ ushort lA[128 * 64];
  __shared__ ushort lB[128 * 64];
  int b = blockIdx.x;
  int tid = threadIdx.x, lane = tid & 63, w = tid >> 6;
  int wm = w >> 1, wn = w & 1;
  int fr = lane & 15, fq = lane >> 4;
  int l8 = lane >> 3, l7 = lane & 7;

  const ushort *A, *B; float* O;
  int ksteps, astride, bstride, t0, n0;
  if (b < 64) {                        // shared
    int mt = b >> 3, nt = b & 7;
    t0 = mt * 128; n0 = nt * 128;
    A = H_sh; astride = 1024; B = swdT; bstride = 1024; ksteps = 16;
    O = out;
  } else if (b < 320) {                // text
    int rel = b - 64; int mt = rel >> 3, nt = rel & 7;
    if (mt >= meta[34]) return;
    int e = meta[40 + mt];
    t0 = mt * 128; n0 = nt * 128;
    A = H_tx; astride = 512;
    B = twdT + (size_t)e * 1024 * 512; bstride = 512; ksteps = 8;
    O = pd_tx;
  } else {                             // vision
    int rel = b - 320; int mt = rel >> 3, nt = rel & 7;
    if (mt >= meta[35]) return;
    int e = meta[72 + mt];
    t0 = mt * 128; n0 = nt * 128;
    A = H_vs; astride = 256;
    B = vwdT + (size_t)e * 1024 * 256; bstride = 256; ksteps = 4;
    O = pd_vs;
  }

  const ushort *aptr[4], *bptr[4];
#pragma unroll
  for (int i = 0; i < 4; ++i) {
    int row = (w * 4 + i) * 8 + l8;
    aptr[i] = A + (size_t)(t0 + row) * astride + l7 * 8;
    bptr[i] = B + (size_t)(n0 + row) * bstride + l7 * 8;
  }

  f32x4 acc[4][4] = {};
  int kend = ksteps * 64;
  for (int k0 = 0; k0 < kend; k0 += 64) {
    if (k0) __syncthreads();
#pragma unroll
    for (int i = 0; i < 4; ++i) {
      gld16(aptr[i] + k0, lA + (w * 4 + i) * 512);
      gld16(bptr[i] + k0, lB + (w * 4 + i) * 512);
    }
    __syncthreads();
#pragma unroll
    for (int kk = 0; kk < 2; ++kk) {
      int kb = kk * 32 + fq * 8;
      bf16x8 a[4], bb[4];
#pragma unroll
      for (int m = 0; m < 4; ++m)
        a[m] = *(const bf16x8*)&lA[(wm * 64 + m * 16 + fr) * 64 + kb];
#pragma unroll
      for (int n = 0; n < 4; ++n)
        bb[n] = *(const bf16x8*)&lB[(wn * 64 + n * 16 + fr) * 64 + kb];
#pragma unroll
      for (int m = 0; m < 4; ++m)
#pragma unroll
        for (int n = 0; n < 4; ++n)
          acc[m][n] = __builtin_amdgcn_mfma_f32_16x16x32_bf16(a[m], bb[n], acc[m][n], 0, 0, 0);
    }
  }

#pragma unroll
  for (int m = 0; m < 4; ++m)
#pragma unroll
    for (int n = 0; n < 4; ++n)
#pragma unroll
      for (int r = 0; r < 4; ++r)
        O[(size_t)(t0 + wm * 64 + m * 16 + fq * 4 + r) * DIM
          + n0 + wn * 64 + n * 16 + fr] = acc[m][n][r];
}

// ---------------------------------------------------------------------------
// Combine: out[t] += w0 * pd[slot0] + w1 * pd[slot1]
// ---------------------------------------------------------------------------
__global__ __launch_bounds__(256) void combine_kernel(
    const int4* __restrict__ ti, const float2* __restrict__ tw,
    const int* __restrict__ meta,
    const float* __restrict__ pd_tx, const float* __restrict__ pd_vs,
    float* __restrict__ out) {
  int t = blockIdx.x;
  int4 v = ti[t]; float2 wv = tw[t];
  int e0 = v.x & 0xff, vis = v.x >> 8, e1 = v.z;
  const int* base = meta + (vis ? 25 : 16);
  const float* pd = vis ? pd_vs : pd_tx;
  size_t s0 = base[e0] + v.y, s1 = base[e1] + v.w;
  int d = threadIdx.x * 4;
  f32x4 a  = *(const f32x4*)(out + (size_t)t * DIM + d);
  f32x4 p0 = *(const f32x4*)(pd + s0 * DIM + d);
  f32x4 p1 = *(const f32x4*)(pd + s1 * DIM + d);
#pragma unroll
  for (int j = 0; j < 4; ++j) a[j] = a[j] + wv.x * p0[j] + wv.y * p1[j];
  *(f32x4*)(out + (size_t)t * DIM + d) = a;
}

// ---------------------------------------------------------------------------
extern "C" void kernel_launch(void* const* d_in, const int* in_sizes, int n_in,
                              void* d_out, int out_size, void* d_ws, size_t ws_size,
                              hipStream_t stream) {
  const float* x    = (const float*)d_in[0];
  const int*   tt   = (const int*)d_in[1];
  const float* t_rw = (const float*)d_in[2];
  const float* t_b  = (const float*)d_in[3];
  const float* t_wg = (const float*)d_in[4];
  const float* t_wu = (const float*)d_in[5];
  const float* t_wd = (const float*)d_in[6];
  const float* v_rw = (const float*)d_in[7];
  const float* v_b  = (const float*)d_in[8];
  const float* v_wg = (const float*)d_in[9];
  const float* v_wu = (const float*)d_in[10];
  const float* v_wd = (const float*)d_in[11];
  const float* s_wg = (const float*)d_in[12];
  const float* s_wu = (const float*)d_in[13];
  const float* s_wd = (const float*)d_in[14];
  float* out    = (float*)d_out;
  float* logits = out + (size_t)1024 * 1024;

  char* p = (char*)d_ws;
  auto alloc = [&](size_t bytes) {
    char* r = p; p += (bytes + 255) & ~(size_t)255; return r;
  };
  ushort* xb     = (ushort*)alloc((size_t)1024 * 1024 * 2);
  int4*   ti     = (int4*)alloc((size_t)1024 * 16);
  float2* tw     = (float2*)alloc((size_t)1024 * 8);
  int*    meta   = (int*)alloc(512 * 4);
  int*    tok_tx = (int*)alloc(MAXSLOT * 4);
  int*    tok_vs = (int*)alloc(MAXSLOT * 4);
  ushort* swdT   = (ushort*)alloc((size_t)1024 * 1024 * 2);
  ushort* twdT   = (ushort*)alloc((size_t)8 * 1024 * 512 * 2);
  ushort* vwdT   = (ushort*)alloc((size_t)8 * 1024 * 256 * 2);
  ushort* H_sh   = (ushort*)alloc((size_t)1024 * 1024 * 2);
  ushort* H_tx   = (ushort*)alloc((size_t)MAXSLOT * 512 * 2);
  ushort* H_vs   = (ushort*)alloc((size_t)MAXSLOT * 256 * 2);
  // union region: up-only weights (28MB) overlaid later by pd buffers (32MB)
  char* upmark = p;
  ushort* swgT   = (ushort*)alloc((size_t)1024 * 1024 * 2);
  ushort* swuT   = (ushort*)alloc((size_t)1024 * 1024 * 2);
  ushort* twgT   = (ushort*)alloc((size_t)8 * 512 * 1024 * 2);
  ushort* twuT   = (ushort*)alloc((size_t)8 * 512 * 1024 * 2);
  ushort* vwgT   = (ushort*)alloc((size_t)8 * 256 * 1024 * 2);
  ushort* vwuT   = (ushort*)alloc((size_t)8 * 256 * 1024 * 2);
  float* pd_tx = (float*)upmark;                       // 16 MB
  float* pd_vs = (float*)(upmark + (size_t)MAXSLOT * DIM * 4);  // 16 MB

  prep_router_kernel<<<PREP_BLOCKS + 256, 256, 0, stream>>>(
      s_wg, s_wu, s_wd, t_wg, t_wu, t_wd, v_wg, v_wu, v_wd,
      swgT, swuT, swdT, twgT, twuT, twdT, vwgT, vwuT, vwdT,
      x, tt, t_rw, t_b, v_rw, v_b, ti, tw, logits, xb);
  finalize_kernel<<<1, 256, 0, stream>>>(meta, ti, tok_tx, tok_vs);
  up_kernel<<<512, 256, 0, stream>>>(xb, swgT, swuT, twgT, twuT, vwgT, vwuT,
                                     meta, tok_tx, tok_vs, H_sh, H_tx, H_vs);
  down_kernel<<<576, 256, 0, stream>>>(H_sh, H_tx, H_vs, swdT, twdT, vwdT,
                                       meta, out, pd_tx, pd_vs);
  combine_kernel<<<1024, 256, 0, stream>>>(ti, tw, meta, pd_tx, pd_vs, out);
}